// Round 9
// baseline (192.786 us; speedup 1.0000x reference)
//
#include <hip/hip_runtime.h>
#include <hip/hip_bf16.h>

// Problem constants (ResNet-50 CBP head)
#define BATCH 8
#define CH    2048
#define LSP   784          // H*W = 28*28
#define KPAD  832          // pad K to 26*32 MFMA k-steps
#define KSTEPS 26          // k-steps of BK=32 (double-buffered)
#define DDIM  8192         // count-sketch dim (power of 2)
#define NCLS  200
#define NTILE 16           // 2048/128 tiles per dim
#define NPAIR 136          // NTILE*(NTILE+1)/2 symmetric tile pairs
#define NSLOT 68           // fallback: part slots per batch (2 blocks/slot)
#define FXSCALE 8192.0f    // fixed-point scale 2^13 (split as 64*128 into meta)
#define FXINV   (1.0f/8192.0f)

typedef _Float16 f16x8 __attribute__((ext_vector_type(8)));
typedef _Float16 f16x4 __attribute__((ext_vector_type(4)));
typedef float    f32x4 __attribute__((ext_vector_type(4)));

#define FATOMIC(p, v) unsafeAtomicAdd((p), (v))

// ---------------------------------------------------------------------------
// Kernel 1: convert x (fp32 [B,C,784]) to fp16 [B,C,KPAD] (zero-pad K).
// 8 elems/thread (2x float4 load, 1x 16B f16x8 store). Also: zero norm,
// bias-seed logits, build packed scatter-meta metaG[c] =
// (s1[c]*64, h1[c], s2[c]*128, h2[c]) (2^13 fixed-point scale rides the
// s1*s2 product), and -- ONLY in atomic-fallback mode -- zero part.
// ---------------------------------------------------------------------------
__global__ __launch_bounds__(256) void split_kernel(
    const float* __restrict__ x,
    _Float16* __restrict__ xh,
    float* __restrict__ part, float* __restrict__ norm,
    const float* __restrict__ s1, const int* __restrict__ h1,
    const float* __restrict__ s2, const int* __restrict__ h2,
    float4* __restrict__ metaG,
    const float* __restrict__ bc, float* __restrict__ out,
    int exclusive)
{
    int idx = blockIdx.x * 256 + threadIdx.x;          // vec8 index
    if (!exclusive && idx < NSLOT * BATCH * DDIM / 4)  // zero part (fallback)
        *(float4*)&part[idx * 4] = make_float4(0.f, 0.f, 0.f, 0.f);
    if (idx < CH)
        metaG[idx] = make_float4(s1[idx] * 64.0f, __int_as_float(h1[idx]),
                                 s2[idx] * 128.0f, __int_as_float(h2[idx]));
    if (idx < BATCH) norm[idx] = 0.0f;
    if (idx < BATCH * NCLS) out[idx] = bc[idx % NCLS]; // bias-seed logits
    if (idx >= BATCH * CH * KPAD / 8) return;
    int v  = idx * 8;
    int bc_ = v / KPAD;
    int l  = v - bc_ * KPAD;                           // multiple of 8
    f16x8 hv = {0, 0, 0, 0, 0, 0, 0, 0};
    if (l < LSP) {                                     // LSP%8==0: uniform per vec
        const float* xp = &x[(size_t)bc_ * LSP + l];
        float4 a = *(const float4*)xp;
        float4 c = *(const float4*)(xp + 4);
        hv[0] = (_Float16)a.x; hv[1] = (_Float16)a.y;
        hv[2] = (_Float16)a.z; hv[3] = (_Float16)a.w;
        hv[4] = (_Float16)c.x; hv[5] = (_Float16)c.y;
        hv[6] = (_Float16)c.z; hv[7] = (_Float16)c.w;
    }
    *(f16x8*)&xh[v] = hv;
}

// ---------------------------------------------------------------------------
// Kernel 2: symmetric Gram tile + count-sketch scatter (int32 LDS histogram).
// R9 theory: the per-stage serial cost (~1050 cyc) is global_load_lds +
// __syncthreads' vmcnt(0) drain exposing the full L2->LDS round trip every
// stage (R7 showed reg-staging is a wash; the drain is the cost). Fix:
// DOUBLE-BUFFERED k-loop with COUNTED vmcnt (T3/T4): issue stage s+1 into
// the alternate buffer, then `s_waitcnt vmcnt(4)` (waits ONLY stage-s loads;
// s+1 stays in flight across the raw s_barrier), compute, barrier, swap.
// BK=32 with R0's proven stage/frag XOR swizzle (bit-identical MFMA order).
// LDS = smA[2]+smB[2] (32 KB) + bins (32 KB) = 64 KB -> 2 blocks/CU kept.
// Scatter: banked ds_add_u32 (R4). Flush: exclusive slot plain stores (R5).
// grid = 1088 x 1 pair (R6 packing: 2.125 rounds, small tail).
// ---------------------------------------------------------------------------
__device__ __forceinline__ void stage_tile(
    const _Float16* __restrict__ src,   // xh + (b*CH + tile*128)*KPAD
    unsigned short* lds_tile,           // 128x32-half tile (one buffer)
    int wv, int lane, int k0)
{
#pragma unroll
    for (int half = 0; half < 2; ++half) {
        int ch  = wv * 2 + half;                       // 0..7 chunk of 8KB tile
        int row = ch * 16 + (lane >> 2);
        int kg  = (lane & 3) ^ ((lane >> 3) & 3);      // XOR swizzle (row>>1)&3
        const _Float16* g = src + (size_t)row * KPAD + k0 + kg * 8;
        __builtin_amdgcn_global_load_lds(
            (__attribute__((address_space(1))) void*)g,
            (__attribute__((address_space(3))) void*)(lds_tile + ch * 512),
            16, 0, 0);
    }
}

__global__ __launch_bounds__(256, 2) void gram_scatter_kernel(
    const _Float16* __restrict__ xh,
    const float4* __restrict__ metaG,
    float* __restrict__ part,
    int exclusive)
{
    __shared__ __align__(16) unsigned short smA[2][128 * 32];  // 16 KB
    __shared__ __align__(16) unsigned short smB[2][128 * 32];  // 16 KB
    __shared__ __align__(16) int bins[DDIM];                   // 32 KB

    const int tid  = threadIdx.x;
    const int lane = tid & 63;
    const int wv   = tid >> 6;
    const int b    = blockIdx.x & 7;       // batch in low bits -> one batch/XCD
    const int pidx = blockIdx.x >> 3;      // triangular pair index

    for (int i = tid; i < DDIM; i += 256) bins[i] = 0;
    // (pipeline's first s_barrier orders this before any ds_add: every wave
    //  zeroes its slice before reaching that barrier, scatter comes after
    //  26 more barriers)

    // Triangular decode: pidx in [0,136) -> (tM, tN), tM <= tN, row-major
    int tM = 0, tN = 0;
    {
        int i = pidx;
#pragma unroll 1
        for (int t = 0; t < NTILE; ++t) {
            int cnt = NTILE - t;
            if (i < cnt) { tM = t; tN = t + i; break; }
            i -= cnt;
        }
    }
    const bool diag = (tM == tN);

    const int wrow = (wv >> 1) * 64;    // wave's 64x64 subtile origin
    const int wcol = (wv & 1) * 64;
    const int rsel = lane & 15;
    const int khi  = lane >> 4;

    const _Float16* srcA = xh + ((size_t)b * CH + (size_t)tM * 128) * KPAD;
    const _Float16* srcB = xh + ((size_t)b * CH + (size_t)tN * 128) * KPAD;

    f32x4 acc[4][4];
    const f32x4 zv = {0.0f, 0.0f, 0.0f, 0.0f};
#pragma unroll
    for (int mi = 0; mi < 4; ++mi)
#pragma unroll
        for (int ni = 0; ni < 4; ++ni) acc[mi][ni] = zv;

    // fragment LDS offset: row*32 + fxor; XOR term is a per-lane constant
    // (matches stage_tile's swizzle: global chunk c of row r lives at LDS
    //  chunk c ^ ((r>>1)&3); (r>>1)&3 == (lane>>1)&3 for frag rows).
    const int fxor = ((khi ^ ((lane >> 1) & 3)) << 3);

    // Prologue: stage 0 into buffer 0.
    stage_tile(srcA, smA[0], wv, lane, 0);
    if (!diag) stage_tile(srcB, smB[0], wv, lane, 0);

#pragma unroll 1
    for (int s = 0; s < KSTEPS; ++s) {
        const int cur = s & 1;
        // Issue stage s+1 into the alternate buffer (in flight across the
        // barrier; the alternate buffer was last read at stage s-1, whose
        // trailing barrier all waves have passed).
        if (s + 1 < KSTEPS) {
            stage_tile(srcA, smA[cur ^ 1], wv, lane, (s + 1) * 32);
            if (!diag) stage_tile(srcB, smB[cur ^ 1], wv, lane, (s + 1) * 32);
            __builtin_amdgcn_sched_barrier(0);
            // Wait for stage-s loads only: exactly the s+1 issues remain.
            if (diag) asm volatile("s_waitcnt vmcnt(2)" ::: "memory");
            else      asm volatile("s_waitcnt vmcnt(4)" ::: "memory");
        } else {
            __builtin_amdgcn_sched_barrier(0);
            asm volatile("s_waitcnt vmcnt(0)" ::: "memory");
        }
        __builtin_amdgcn_s_barrier();      // all waves' stage-s loads landed
        __builtin_amdgcn_sched_barrier(0);

        const unsigned short* bufA = smA[cur];
        const unsigned short* bufB = diag ? smA[cur] : smB[cur];
        f16x8 ah[4], bh[4];
#pragma unroll
        for (int i = 0; i < 4; ++i) {
            ah[i] = *(const f16x8*)&bufA[(wrow + i * 16 + rsel) * 32 + fxor];
            bh[i] = *(const f16x8*)&bufB[(wcol + i * 16 + rsel) * 32 + fxor];
        }
#pragma unroll
        for (int mi = 0; mi < 4; ++mi)
#pragma unroll
            for (int ni = 0; ni < 4; ++ni)
                acc[mi][ni] = __builtin_amdgcn_mfma_f32_16x16x32_f16(
                    ah[mi], bh[ni], acc[mi][ni], 0, 0, 0);

        __builtin_amdgcn_sched_barrier(0);
        __builtin_amdgcn_s_barrier();      // reads done before buffer reuse
    }

    // Column meta: one packed float4 per c2 (VMEM, L2-hot). s-values carry
    // the fixed-point scale (s1*64, s2*128).
    const int c2b = tN * 128 + wcol + rsel;
    int   h1c[4], h2c[4]; float s1c[4], s2c[4];
#pragma unroll
    for (int ni = 0; ni < 4; ++ni) {
        float4 cm = metaG[c2b + ni * 16];
        s1c[ni] = cm.x; h1c[ni] = __float_as_int(cm.y);
        s2c[ni] = cm.z; h2c[ni] = __float_as_int(cm.w);
    }

    // Scatter the 128x128 Gram tile into the LDS int histogram.
    // C/D layout (m89-verified): col = lane&15, row = (lane>>4)*4 + reg
    // Row meta also via VMEM -> zero lgkmcnt-ordered ops between ds_adds.
    const int rowbase = tM * 128 + wrow + (khi << 2);
#pragma unroll
    for (int mi = 0; mi < 4; ++mi) {
        float4 rm[4];
#pragma unroll
        for (int r = 0; r < 4; ++r) rm[r] = metaG[rowbase + mi * 16 + r];
#pragma unroll
        for (int r = 0; r < 4; ++r) {
            const float s1r = rm[r].x, s2r = rm[r].z;
            const int h1r = __float_as_int(rm[r].y);
            const int h2r = __float_as_int(rm[r].w);
#pragma unroll
            for (int ni = 0; ni < 4; ++ni) {
                float g = acc[mi][ni][r];
                atomicAdd(&bins[(h1r + h2c[ni]) & (DDIM - 1)],
                          (int)(s1r * s2c[ni] * g));
                if (!diag)
                    atomicAdd(&bins[(h1c[ni] + h2r) & (DDIM - 1)],
                              (int)(s1c[ni] * s2r * g));
            }
        }
    }

    __syncthreads();   // all scatters into bins complete

    if (exclusive) {
        // Exclusive slot (one block per (pidx,b)): plain coalesced stores.
        float* pbase = part + ((size_t)(pidx * BATCH + b) * DDIM);
#pragma unroll 4
        for (int i = tid; i < DDIM / 4; i += 256) {
            int4 v = *(const int4*)&bins[i * 4];
            float4 f = make_float4((float)v.x * FXINV, (float)v.y * FXINV,
                                   (float)v.z * FXINV, (float)v.w * FXINV);
            *(float4*)&pbase[i * 4] = f;
        }
    } else {
        // Fallback: 68 shared slots, fp32 global atomics, rotated start.
        float* pbase = part + ((size_t)((pidx % NSLOT) * BATCH + b) * DDIM);
        const int rot = (blockIdx.x & 31) << 8;
        for (int i = tid; i < DDIM; i += 256) {
            int j = (i + rot) & (DDIM - 1);
            int v = bins[j];
            if (v != 0) FATOMIC(&pbase[j], (float)v * FXINV);
        }
    }
}

// ---------------------------------------------------------------------------
// Kernel 3: y[b,d] = sum over nslots part slots; norm[b] += sum|y|.
// grid 256 x 256: one scalar float per thread, all CUs active.
// batch = blockIdx&7 keeps reads on the XCD whose L2 holds that batch's part.
// NOTE: overwrites y, whose first 32 KB doubled as metaG for the (already
// finished) gram kernel -- intentional workspace reuse.
// ---------------------------------------------------------------------------
__global__ __launch_bounds__(256) void reduce_kernel(
    const float* __restrict__ part, float* __restrict__ y,
    float* __restrict__ norm, int nslots)
{
    const int tid = threadIdx.x;
    const int b   = blockIdx.x & 7;
    const int d0  = (blockIdx.x >> 3) * 256 + tid;     // scalar float index
    float s = 0.0f;
#pragma unroll 8
    for (int p = 0; p < nslots; ++p)
        s += part[((size_t)p * BATCH + b) * DDIM + d0];
    y[(size_t)b * DDIM + d0] = s;
    float ab = fabsf(s);
    __shared__ float red[256];
    red[tid] = ab;
    __syncthreads();
    for (int st = 128; st > 0; st >>= 1) {
        if (tid < st) red[tid] += red[tid + st];
        __syncthreads();
    }
    if (tid == 0) FATOMIC(&norm[b], red[0]);   // sum|y| == sum feat_unnorm^2
}

// ---------------------------------------------------------------------------
// Kernel 4: fused signed-sqrt + L2-normalize + classifier GEMV.
// grid 64: block j owns d in [128j, 128j+128) for all batches.
// ---------------------------------------------------------------------------
__global__ __launch_bounds__(256) void logit_kernel(
    const float* __restrict__ y, const float* __restrict__ norm,
    const float* __restrict__ W, float* __restrict__ out)
{
    const int j = blockIdx.x;
    const int tid = threadIdx.x;
    __shared__ float fs[BATCH][128];                   // 4 KB
    for (int i = tid; i < BATCH * 128; i += 256) {
        int bb = i >> 7, dd = i & 127;
        float v = y[(size_t)bb * DDIM + j * 128 + dd];
        float inv = 1.0f / fmaxf(sqrtf(norm[bb]), 1e-12f);
        float f = copysignf(sqrtf(fabsf(v)), v) * inv;
        fs[bb][dd] = f;
        out[BATCH * NCLS + (size_t)bb * DDIM + j * 128 + dd] = f;
    }
    __syncthreads();
    if (tid < NCLS) {
        float a[BATCH];
#pragma unroll
        for (int bb = 0; bb < BATCH; ++bb) a[bb] = 0.0f;
        for (int dd = 0; dd < 128; ++dd) {
            float w = W[(size_t)(j * 128 + dd) * NCLS + tid];
#pragma unroll
            for (int bb = 0; bb < BATCH; ++bb) a[bb] += fs[bb][dd] * w;
        }
#pragma unroll
        for (int bb = 0; bb < BATCH; ++bb)
            FATOMIC(&out[bb * NCLS + tid], a[bb]);
    }
}

// ---------------------------------------------------------------------------
extern "C" void kernel_launch(void* const* d_in, const int* in_sizes, int n_in,
                              void* d_out, int out_size, void* d_ws, size_t ws_size,
                              hipStream_t stream)
{
    const float* x  = (const float*)d_in[0];
    const float* s1 = (const float*)d_in[1];
    const float* s2 = (const float*)d_in[2];
    const float* W  = (const float*)d_in[3];
    const float* bc = (const float*)d_in[4];
    const int*   h1 = (const int*)d_in[5];
    const int*   h2 = (const int*)d_in[6];
    float* out = (float*)d_out;

    const size_t ybytes  = (size_t)BATCH * DDIM * sizeof(float);
    const size_t xhbytes = (size_t)BATCH * CH * KPAD * sizeof(_Float16);

    // Prefer exclusive mode: part = 136 slots (34 MB), plain-store flush.
    // Fallback (ws too small): 68 shared slots + atomic flush.
    size_t partbytes = (size_t)NPAIR * BATCH * DDIM * sizeof(float);
    int exclusive = (ws_size >= partbytes + ybytes + 128 + xhbytes);
    if (!exclusive)
        partbytes = (size_t)NSLOT * BATCH * DDIM * sizeof(float);
    const int nslots = exclusive ? NPAIR : NSLOT;

    // ws layout: part | y (first 32KB doubles as metaG until reduce) | norm | xh
    char* ws = (char*)d_ws;
    float* part = (float*)ws;
    float* y    = (float*)(ws + partbytes);
    float4* metaG = (float4*)(ws + partbytes);         // overlay on y region
    float* norm = (float*)(ws + partbytes + ybytes);
    _Float16* xh = (_Float16*)(ws + partbytes + ybytes + 128);

    split_kernel<<<(BATCH * CH * KPAD / 8 + 255) / 256, 256, 0, stream>>>(
        x, xh, part, norm, s1, h1, s2, h2, metaG, bc, out, exclusive);

    gram_scatter_kernel<<<NPAIR * BATCH, 256, 0, stream>>>(
        xh, metaG, part, exclusive);

    reduce_kernel<<<256, 256, 0, stream>>>(part, y, norm, nslots);

    logit_kernel<<<64, 256, 0, stream>>>(y, norm, W, out);
}

// Round 10
// 175.986 us; speedup vs baseline: 1.0955x; 1.0955x over previous
//
#include <hip/hip_runtime.h>
#include <hip/hip_bf16.h>

// Problem constants (ResNet-50 CBP head)
#define BATCH 8
#define CH    2048
#define LSP   784          // H*W = 28*28
#define KPAD  832          // pad K to 13*64: full-128B-line k-stages
#define KSTAGE 13          // k-stages of BK=64 (2 MFMA k-substeps each)
#define DDIM  8192         // count-sketch dim (power of 2)
#define NCLS  200
#define NTILE 16           // 2048/128 tiles per dim
#define NPAIR 136          // NTILE*(NTILE+1)/2 symmetric tile pairs
#define NSLOT 68           // fallback: part slots per batch (2 blocks/slot)
#define FXSCALE 8192.0f    // fixed-point scale 2^13 (split as 64*128 into meta)
#define FXINV   (1.0f/8192.0f)

typedef _Float16 f16x8 __attribute__((ext_vector_type(8)));
typedef _Float16 f16x4 __attribute__((ext_vector_type(4)));
typedef float    f32x4 __attribute__((ext_vector_type(4)));

#define FATOMIC(p, v) unsafeAtomicAdd((p), (v))

// ---------------------------------------------------------------------------
// Kernel 1: convert x (fp32 [B,C,784]) to fp16 [B,C,KPAD] (zero-pad K).
// 8 elems/thread (2x float4 load, 1x 16B f16x8 store). Also: zero norm,
// bias-seed logits, build packed scatter-meta metaG[c] =
// (s1[c]*64, h1[c], s2[c]*128, h2[c]) (2^13 fixed-point scale rides the
// s1*s2 product), and -- ONLY in atomic-fallback mode -- zero part.
// ---------------------------------------------------------------------------
__global__ __launch_bounds__(256) void split_kernel(
    const float* __restrict__ x,
    _Float16* __restrict__ xh,
    float* __restrict__ part, float* __restrict__ norm,
    const float* __restrict__ s1, const int* __restrict__ h1,
    const float* __restrict__ s2, const int* __restrict__ h2,
    float4* __restrict__ metaG,
    const float* __restrict__ bc, float* __restrict__ out,
    int exclusive)
{
    int idx = blockIdx.x * 256 + threadIdx.x;          // vec8 index
    if (!exclusive && idx < NSLOT * BATCH * DDIM / 4)  // zero part (fallback)
        *(float4*)&part[idx * 4] = make_float4(0.f, 0.f, 0.f, 0.f);
    if (idx < CH)
        metaG[idx] = make_float4(s1[idx] * 64.0f, __int_as_float(h1[idx]),
                                 s2[idx] * 128.0f, __int_as_float(h2[idx]));
    if (idx < BATCH) norm[idx] = 0.0f;
    if (idx < BATCH * NCLS) out[idx] = bc[idx % NCLS]; // bias-seed logits
    if (idx >= BATCH * CH * KPAD / 8) return;
    int v  = idx * 8;
    int bc_ = v / KPAD;
    int l  = v - bc_ * KPAD;                           // multiple of 8
    f16x8 hv = {0, 0, 0, 0, 0, 0, 0, 0};
    if (l < LSP) {                                     // LSP%8==0: uniform per vec
        const float* xp = &x[(size_t)bc_ * LSP + l];
        float4 a = *(const float4*)xp;
        float4 c = *(const float4*)(xp + 4);
        hv[0] = (_Float16)a.x; hv[1] = (_Float16)a.y;
        hv[2] = (_Float16)a.z; hv[3] = (_Float16)a.w;
        hv[4] = (_Float16)c.x; hv[5] = (_Float16)c.y;
        hv[6] = (_Float16)c.z; hv[7] = (_Float16)c.w;
    }
    *(f16x8*)&xh[v] = hv;
}

// ---------------------------------------------------------------------------
// Kernel 2: symmetric Gram tile + count-sketch scatter (int32 LDS histogram).
// R10: EXACT restore of R6's proven structure (58 us) -- full-128B-line
// global_load_lds staging (13 stages of BK=64), XOR-swizzled LDS reads,
// simple {stage -> sync -> 2x(8 ds_read_b128 + 16 MFMA) -> sync} loop.
// R7 (reg-staging), R8 (2-pair blocks), R9 (BK=32 dbuf+counted vmcnt) all
// lost to this: the 1088x1-pair grid packs at 0.99 utilization and the
// full-line staging keeps FETCH at ~14.5 MB (R9's half-line = 23.9 MB).
// Scatter: banked ds_add_u32 (R4: ds FP-atomics are ~4.5cyc serial; int is
// banked). Flush: exclusive 136-slot plain stores (R5).
// LDS 64 KB (smA 16 + smB 16 + bins 32) -> 2 blocks/CU.
// grid = 1088: batch = id&7 (one batch per XCD), pair = id>>3.
// ---------------------------------------------------------------------------
__device__ __forceinline__ void stage64(
    const _Float16* __restrict__ src,   // xh + (b*CH + tile*128)*KPAD
    unsigned short* lds,                // 128x64-half tile, linear
    int wv, int lane, int s)
{
    const int rowi = lane >> 3;             // 0..7: row within instruction
    const int gc   = (lane & 7) ^ rowi;     // pre-swizzled global 8-half chunk
    const _Float16* g0 = src + (size_t)rowi * KPAD + s * 64 + gc * 8;
#pragma unroll
    for (int q = 0; q < 4; ++q) {
        const int r0 = wv * 32 + q * 8;     // 8 rows per instruction
        __builtin_amdgcn_global_load_lds(
            (__attribute__((address_space(1))) void*)(g0 + (size_t)r0 * KPAD),
            (__attribute__((address_space(3))) void*)(lds + r0 * 64),
            16, 0, 0);
    }
}

__global__ __launch_bounds__(256, 2) void gram_scatter_kernel(
    const _Float16* __restrict__ xh,
    const float4* __restrict__ metaG,
    float* __restrict__ part,
    int exclusive)
{
    __shared__ __align__(16) unsigned short smA[128 * 64];   // 16 KB
    __shared__ __align__(16) unsigned short smB[128 * 64];   // 16 KB
    __shared__ __align__(16) int bins[DDIM];                 // 32 KB

    const int tid  = threadIdx.x;
    const int lane = tid & 63;
    const int wv   = tid >> 6;
    const int b    = blockIdx.x & 7;       // batch in low bits -> one batch/XCD
    const int pidx = blockIdx.x >> 3;      // triangular pair index

    for (int i = tid; i < DDIM; i += 256) bins[i] = 0;
    // (first stage's __syncthreads orders this before any ds_add)

    // Triangular decode: pidx in [0,136) -> (tM, tN), tM <= tN, row-major
    int tM = 0, tN = 0;
    {
        int i = pidx;
#pragma unroll 1
        for (int t = 0; t < NTILE; ++t) {
            int cnt = NTILE - t;
            if (i < cnt) { tM = t; tN = t + i; break; }
            i -= cnt;
        }
    }
    const bool diag = (tM == tN);

    const int wrow = (wv >> 1) * 64;    // wave's 64x64 subtile origin
    const int wcol = (wv & 1) * 64;
    const int rsel = lane & 15;
    const int khi  = lane >> 4;         // k 8-half group within a k-substep

    const _Float16* srcA = xh + ((size_t)b * CH + (size_t)tM * 128) * KPAD;
    const _Float16* srcB = xh + ((size_t)b * CH + (size_t)tN * 128) * KPAD;
    const unsigned short* fragB = diag ? smA : smB;

    f32x4 acc[4][4];
    const f32x4 zv = {0.0f, 0.0f, 0.0f, 0.0f};
#pragma unroll
    for (int mi = 0; mi < 4; ++mi)
#pragma unroll
        for (int ni = 0; ni < 4; ++ni) acc[mi][ni] = zv;

    // Staged k-loop: 13 stages x {stage 16(32)KB, barrier, 2x(8 ds_read_b128
    // + 16 MFMA), barrier}.
#pragma unroll 1
    for (int s = 0; s < KSTAGE; ++s) {
        stage64(srcA, smA, wv, lane, s);
        if (!diag) stage64(srcB, smB, wv, lane, s);
        __syncthreads();                 // loads landed, all waves ready
#pragma unroll
        for (int t = 0; t < 2; ++t) {
            // swizzled chunk: global chunk (t*4+khi) lives at LDS chunk
            // (t*4+khi)^(row&7); row&7 == rsel&7 for all fragments here.
            const int co = ((((t << 2) + khi) ^ (rsel & 7)) << 3);
            f16x8 ah[4], bh[4];
#pragma unroll
            for (int i = 0; i < 4; ++i) {
                ah[i] = *(const f16x8*)&smA[(wrow + i * 16 + rsel) * 64 + co];
                bh[i] = *(const f16x8*)&fragB[(wcol + i * 16 + rsel) * 64 + co];
            }
#pragma unroll
            for (int mi = 0; mi < 4; ++mi)
#pragma unroll
                for (int ni = 0; ni < 4; ++ni)
                    acc[mi][ni] = __builtin_amdgcn_mfma_f32_16x16x32_f16(
                        ah[mi], bh[ni], acc[mi][ni], 0, 0, 0);
        }
        __syncthreads();                 // all reads done before next stage
    }

    // Column meta: one packed float4 per c2 (VMEM, L2-hot). s-values carry
    // the fixed-point scale (s1*64, s2*128).
    const int c2b = tN * 128 + wcol + rsel;
    int   h1c[4], h2c[4]; float s1c[4], s2c[4];
#pragma unroll
    for (int ni = 0; ni < 4; ++ni) {
        float4 cm = metaG[c2b + ni * 16];
        s1c[ni] = cm.x; h1c[ni] = __float_as_int(cm.y);
        s2c[ni] = cm.z; h2c[ni] = __float_as_int(cm.w);
    }

    // Scatter the 128x128 Gram tile into the LDS int histogram.
    // C/D layout (m89-verified): col = lane&15, row = (lane>>4)*4 + reg
    // Row meta also via VMEM -> zero lgkmcnt-ordered ops between ds_adds.
    const int rowbase = tM * 128 + wrow + (khi << 2);
#pragma unroll
    for (int mi = 0; mi < 4; ++mi) {
        float4 rm[4];
#pragma unroll
        for (int r = 0; r < 4; ++r) rm[r] = metaG[rowbase + mi * 16 + r];
#pragma unroll
        for (int r = 0; r < 4; ++r) {
            const float s1r = rm[r].x, s2r = rm[r].z;
            const int h1r = __float_as_int(rm[r].y);
            const int h2r = __float_as_int(rm[r].w);
#pragma unroll
            for (int ni = 0; ni < 4; ++ni) {
                float g = acc[mi][ni][r];
                atomicAdd(&bins[(h1r + h2c[ni]) & (DDIM - 1)],
                          (int)(s1r * s2c[ni] * g));
                if (!diag)
                    atomicAdd(&bins[(h1c[ni] + h2r) & (DDIM - 1)],
                              (int)(s1c[ni] * s2r * g));
            }
        }
    }

    __syncthreads();   // all scatters into bins complete

    if (exclusive) {
        // Exclusive slot (one block per (pidx,b)): plain coalesced stores.
        float* pbase = part + ((size_t)(pidx * BATCH + b) * DDIM);
#pragma unroll 4
        for (int i = tid; i < DDIM / 4; i += 256) {
            int4 v = *(const int4*)&bins[i * 4];
            float4 f = make_float4((float)v.x * FXINV, (float)v.y * FXINV,
                                   (float)v.z * FXINV, (float)v.w * FXINV);
            *(float4*)&pbase[i * 4] = f;
        }
    } else {
        // Fallback: 68 shared slots, fp32 global atomics, rotated start.
        float* pbase = part + ((size_t)((pidx % NSLOT) * BATCH + b) * DDIM);
        const int rot = (blockIdx.x & 31) << 8;
        for (int i = tid; i < DDIM; i += 256) {
            int j = (i + rot) & (DDIM - 1);
            int v = bins[j];
            if (v != 0) FATOMIC(&pbase[j], (float)v * FXINV);
        }
    }
}

// ---------------------------------------------------------------------------
// Kernel 3: y[b,d] = sum over nslots part slots; norm[b] += sum|y|.
// grid 256 x 256: one scalar float per thread, all CUs active.
// batch = blockIdx&7 keeps reads on the XCD whose L2 holds that batch's part.
// NOTE: overwrites y, whose first 32 KB doubled as metaG for the (already
// finished) gram kernel -- intentional workspace reuse.
// ---------------------------------------------------------------------------
__global__ __launch_bounds__(256) void reduce_kernel(
    const float* __restrict__ part, float* __restrict__ y,
    float* __restrict__ norm, int nslots)
{
    const int tid = threadIdx.x;
    const int b   = blockIdx.x & 7;
    const int d0  = (blockIdx.x >> 3) * 256 + tid;     // scalar float index
    float s = 0.0f;
#pragma unroll 8
    for (int p = 0; p < nslots; ++p)
        s += part[((size_t)p * BATCH + b) * DDIM + d0];
    y[(size_t)b * DDIM + d0] = s;
    float ab = fabsf(s);
    __shared__ float red[256];
    red[tid] = ab;
    __syncthreads();
    for (int st = 128; st > 0; st >>= 1) {
        if (tid < st) red[tid] += red[tid + st];
        __syncthreads();
    }
    if (tid == 0) FATOMIC(&norm[b], red[0]);   // sum|y| == sum feat_unnorm^2
}

// ---------------------------------------------------------------------------
// Kernel 4: fused signed-sqrt + L2-normalize + classifier GEMV.
// R10: grid 128 (was 64): block j owns d in [64j, 64j+64) for all batches --
// doubles the CUs streaming the 6.6 MB W matrix (the dominant read here)
// and halves each block's serial GEMV tail. inv-norm hoisted per batch.
// ---------------------------------------------------------------------------
__global__ __launch_bounds__(256) void logit_kernel(
    const float* __restrict__ y, const float* __restrict__ norm,
    const float* __restrict__ W, float* __restrict__ out)
{
    const int j = blockIdx.x;
    const int tid = threadIdx.x;
    __shared__ float fs[BATCH][64];                    // 2 KB
    __shared__ float inv[BATCH];
    if (tid < BATCH) inv[tid] = 1.0f / fmaxf(sqrtf(norm[tid]), 1e-12f);
    __syncthreads();
    for (int i = tid; i < BATCH * 64; i += 256) {
        int bb = i >> 6, dd = i & 63;
        float v = y[(size_t)bb * DDIM + j * 64 + dd];
        float f = copysignf(sqrtf(fabsf(v)), v) * inv[bb];
        fs[bb][dd] = f;
        out[BATCH * NCLS + (size_t)bb * DDIM + j * 64 + dd] = f;
    }
    __syncthreads();
    if (tid < NCLS) {
        float a[BATCH];
#pragma unroll
        for (int bb = 0; bb < BATCH; ++bb) a[bb] = 0.0f;
        for (int dd = 0; dd < 64; ++dd) {
            float w = W[(size_t)(j * 64 + dd) * NCLS + tid];
#pragma unroll
            for (int bb = 0; bb < BATCH; ++bb) a[bb] += fs[bb][dd] * w;
        }
#pragma unroll
        for (int bb = 0; bb < BATCH; ++bb)
            FATOMIC(&out[bb * NCLS + tid], a[bb]);
    }
}

// ---------------------------------------------------------------------------
extern "C" void kernel_launch(void* const* d_in, const int* in_sizes, int n_in,
                              void* d_out, int out_size, void* d_ws, size_t ws_size,
                              hipStream_t stream)
{
    const float* x  = (const float*)d_in[0];
    const float* s1 = (const float*)d_in[1];
    const float* s2 = (const float*)d_in[2];
    const float* W  = (const float*)d_in[3];
    const float* bc = (const float*)d_in[4];
    const int*   h1 = (const int*)d_in[5];
    const int*   h2 = (const int*)d_in[6];
    float* out = (float*)d_out;

    const size_t ybytes  = (size_t)BATCH * DDIM * sizeof(float);
    const size_t xhbytes = (size_t)BATCH * CH * KPAD * sizeof(_Float16);

    // Prefer exclusive mode: part = 136 slots (34 MB), plain-store flush.
    // Fallback (ws too small): 68 shared slots + atomic flush.
    size_t partbytes = (size_t)NPAIR * BATCH * DDIM * sizeof(float);
    int exclusive = (ws_size >= partbytes + ybytes + 128 + xhbytes);
    if (!exclusive)
        partbytes = (size_t)NSLOT * BATCH * DDIM * sizeof(float);
    const int nslots = exclusive ? NPAIR : NSLOT;

    // ws layout: part | y (first 32KB doubles as metaG until reduce) | norm | xh
    char* ws = (char*)d_ws;
    float* part = (float*)ws;
    float* y    = (float*)(ws + partbytes);
    float4* metaG = (float4*)(ws + partbytes);         // overlay on y region
    float* norm = (float*)(ws + partbytes + ybytes);
    _Float16* xh = (_Float16*)(ws + partbytes + ybytes + 128);

    split_kernel<<<(BATCH * CH * KPAD / 8 + 255) / 256, 256, 0, stream>>>(
        x, xh, part, norm, s1, h1, s2, h2, metaG, bc, out, exclusive);

    gram_scatter_kernel<<<NPAIR * BATCH, 256, 0, stream>>>(
        xh, metaG, part, exclusive);

    reduce_kernel<<<256, 256, 0, stream>>>(part, y, norm, nslots);

    logit_kernel<<<128, 256, 0, stream>>>(y, norm, W, out);
}

// Round 11
// 172.004 us; speedup vs baseline: 1.1208x; 1.0231x over previous
//
#include <hip/hip_runtime.h>
#include <hip/hip_bf16.h>

// Problem constants (ResNet-50 CBP head)
#define BATCH 8
#define CH    2048
#define LSP   784          // H*W = 28*28
#define KPAD  832          // pad K to 13*64: full-128B-line k-stages
#define KSTAGE 13          // k-stages of BK=64 (2 MFMA k-substeps each)
#define DDIM  8192         // count-sketch dim (power of 2)
#define NCLS  200
#define NTILE 16           // 2048/128 tiles per dim
#define NGRID 1024         // gram grid: 64 double-diag blocks + 960 off-diag
#define NSLOTX 128         // exclusive: part slots per batch (= NGRID/8)
#define NSLOTF 64          // fallback: shared slots per batch (atomic flush)
#define FXSCALE 8192.0f    // fixed-point scale 2^13 (split as 64*128 into meta)
#define FXINV   (1.0f/8192.0f)

typedef _Float16 f16x8 __attribute__((ext_vector_type(8)));
typedef _Float16 f16x4 __attribute__((ext_vector_type(4)));
typedef float    f32x4 __attribute__((ext_vector_type(4)));

#define FATOMIC(p, v) unsafeAtomicAdd((p), (v))

// ---------------------------------------------------------------------------
// Kernel 1: convert x (fp32 [B,C,784]) to fp16 [B,C,KPAD] (zero-pad K).
// 8 elems/thread (2x float4 load, 1x 16B f16x8 store). Also: zero norm,
// bias-seed logits, build packed scatter-meta metaG[c] =
// (s1[c]*64, h1[c], s2[c]*128, h2[c]) (2^13 fixed-point scale rides the
// s1*s2 product), and -- ONLY in atomic-fallback mode -- zero part.
// ---------------------------------------------------------------------------
__global__ __launch_bounds__(256) void split_kernel(
    const float* __restrict__ x,
    _Float16* __restrict__ xh,
    float* __restrict__ part, float* __restrict__ norm,
    const float* __restrict__ s1, const int* __restrict__ h1,
    const float* __restrict__ s2, const int* __restrict__ h2,
    float4* __restrict__ metaG,
    const float* __restrict__ bc, float* __restrict__ out,
    int exclusive)
{
    int idx = blockIdx.x * 256 + threadIdx.x;          // vec8 index
    if (!exclusive && idx < NSLOTF * BATCH * DDIM / 4) // zero part (fallback)
        *(float4*)&part[idx * 4] = make_float4(0.f, 0.f, 0.f, 0.f);
    if (idx < CH)
        metaG[idx] = make_float4(s1[idx] * 64.0f, __int_as_float(h1[idx]),
                                 s2[idx] * 128.0f, __int_as_float(h2[idx]));
    if (idx < BATCH) norm[idx] = 0.0f;
    if (idx < BATCH * NCLS) out[idx] = bc[idx % NCLS]; // bias-seed logits
    if (idx >= BATCH * CH * KPAD / 8) return;
    int v  = idx * 8;
    int bc_ = v / KPAD;
    int l  = v - bc_ * KPAD;                           // multiple of 8
    f16x8 hv = {0, 0, 0, 0, 0, 0, 0, 0};
    if (l < LSP) {                                     // LSP%8==0: uniform per vec
        const float* xp = &x[(size_t)bc_ * LSP + l];
        float4 a = *(const float4*)xp;
        float4 c = *(const float4*)(xp + 4);
        hv[0] = (_Float16)a.x; hv[1] = (_Float16)a.y;
        hv[2] = (_Float16)a.z; hv[3] = (_Float16)a.w;
        hv[4] = (_Float16)c.x; hv[5] = (_Float16)c.y;
        hv[6] = (_Float16)c.z; hv[7] = (_Float16)c.w;
    }
    *(f16x8*)&xh[v] = hv;
}

// ---------------------------------------------------------------------------
// Kernel 2: symmetric Gram tiles + count-sketch scatter (int32 LDS histogram).
// R11: PACKING FIX. R6/R10's 1088 blocks on 512 CU-slots = 2 rounds + 64
// stragglers -> wall = 3x block-time (cross-round fit: T1~20us, wall 60us;
// R8: T2~35us, wall 70us). New grid = 1024 = EXACTLY 2 rounds:
//   blocks 0..63   : TWO diagonal pairs each (cheap: 1 tile staged, half
//                    scatter; ~1.3-1.4x T1 combined), shared bins, one flush
//   blocks 64..1023: one off-diagonal pair each (T1)
// -> slot wall ~ 2.3x T1 instead of 3x T1. K-loop/scatter/flush bodies are
// byte-identical to R10 (R6's proven 58us structure: full-128B-line
// global_load_lds, XOR-swizzled ds_read_b128, banked ds_add_u32 scatter,
// exclusive-slot plain-store flush).
// LDS 64 KB (smA 16 + smB 16 + bins 32) -> 2 blocks/CU.
// batch = bid&7 (one batch per XCD; 64%8==0 keeps this for off-diag too).
// ---------------------------------------------------------------------------
__device__ __forceinline__ void stage64(
    const _Float16* __restrict__ src,   // xh + (b*CH + tile*128)*KPAD
    unsigned short* lds,                // 128x64-half tile, linear
    int wv, int lane, int s)
{
    const int rowi = lane >> 3;             // 0..7: row within instruction
    const int gc   = (lane & 7) ^ rowi;     // pre-swizzled global 8-half chunk
    const _Float16* g0 = src + (size_t)rowi * KPAD + s * 64 + gc * 8;
#pragma unroll
    for (int q = 0; q < 4; ++q) {
        const int r0 = wv * 32 + q * 8;     // 8 rows per instruction
        __builtin_amdgcn_global_load_lds(
            (__attribute__((address_space(1))) void*)(g0 + (size_t)r0 * KPAD),
            (__attribute__((address_space(3))) void*)(lds + r0 * 64),
            16, 0, 0);
    }
}

__global__ __launch_bounds__(256, 2) void gram_scatter_kernel(
    const _Float16* __restrict__ xh,
    const float4* __restrict__ metaG,
    float* __restrict__ part,
    int exclusive)
{
    __shared__ __align__(16) unsigned short smA[128 * 64];   // 16 KB
    __shared__ __align__(16) unsigned short smB[128 * 64];   // 16 KB
    __shared__ __align__(16) int bins[DDIM];                 // 32 KB

    const int tid  = threadIdx.x;
    const int lane = tid & 63;
    const int wv   = tid >> 6;
    const int bid  = blockIdx.x;
    const int b    = bid & 7;              // batch in low bits -> one batch/XCD

    for (int i = tid; i < DDIM; i += 256) bins[i] = 0;
    // (first stage's __syncthreads orders this before any ds_add)

    // Job list: blocks <64 take two diag pairs (2t, 2t+1); others one
    // strict-upper off-diag pair decoded row-major over 120 entries.
    int npair, tMs[2], tNs[2];
    if (bid < 64) {
        const int t2 = (bid >> 3) * 2;
        npair = 2;
        tMs[0] = tNs[0] = t2;
        tMs[1] = tNs[1] = t2 + 1;
    } else {
        npair = 1;
        int i = (bid - 64) >> 3;           // 0..119
        int tM = 0, tN = 0;
#pragma unroll 1
        for (int t = 0; t < NTILE - 1; ++t) {
            int cnt = NTILE - 1 - t;       // 15-t strict-upper entries in row t
            if (i < cnt) { tM = t; tN = t + 1 + i; break; }
            i -= cnt;
        }
        tMs[0] = tM; tNs[0] = tN;
    }

    const int wrow = (wv >> 1) * 64;    // wave's 64x64 subtile origin
    const int wcol = (wv & 1) * 64;
    const int rsel = lane & 15;
    const int khi  = lane >> 4;         // k 8-half group within a k-substep

#pragma unroll 1
    for (int pp = 0; pp < npair; ++pp) {
        const int tM = tMs[pp], tN = tNs[pp];
        const bool diag = (tM == tN);

        const _Float16* srcA = xh + ((size_t)b * CH + (size_t)tM * 128) * KPAD;
        const _Float16* srcB = xh + ((size_t)b * CH + (size_t)tN * 128) * KPAD;
        const unsigned short* fragB = diag ? smA : smB;

        f32x4 acc[4][4];
        const f32x4 zv = {0.0f, 0.0f, 0.0f, 0.0f};
#pragma unroll
        for (int mi = 0; mi < 4; ++mi)
#pragma unroll
            for (int ni = 0; ni < 4; ++ni) acc[mi][ni] = zv;

        // Staged k-loop: 13 stages x {stage 16(32)KB, barrier, 2x(8
        // ds_read_b128 + 16 MFMA), barrier}. Safe across pairs: scatter
        // touches only bins/VMEM, staging touches only smA/smB, and the
        // stage-0 __syncthreads orders everything (vmcnt drained there).
#pragma unroll 1
        for (int s = 0; s < KSTAGE; ++s) {
            stage64(srcA, smA, wv, lane, s);
            if (!diag) stage64(srcB, smB, wv, lane, s);
            __syncthreads();                 // loads landed, all waves ready
#pragma unroll
            for (int t = 0; t < 2; ++t) {
                // swizzled chunk: global chunk (t*4+khi) lives at LDS chunk
                // (t*4+khi)^(row&7); row&7 == rsel&7 for all fragments here.
                const int co = ((((t << 2) + khi) ^ (rsel & 7)) << 3);
                f16x8 ah[4], bh[4];
#pragma unroll
                for (int i = 0; i < 4; ++i) {
                    ah[i] = *(const f16x8*)&smA[(wrow + i * 16 + rsel) * 64 + co];
                    bh[i] = *(const f16x8*)&fragB[(wcol + i * 16 + rsel) * 64 + co];
                }
#pragma unroll
                for (int mi = 0; mi < 4; ++mi)
#pragma unroll
                    for (int ni = 0; ni < 4; ++ni)
                        acc[mi][ni] = __builtin_amdgcn_mfma_f32_16x16x32_f16(
                            ah[mi], bh[ni], acc[mi][ni], 0, 0, 0);
            }
            __syncthreads();                 // all reads done before next stage
        }

        // Column meta: one packed float4 per c2 (VMEM, L2-hot). s-values
        // carry the fixed-point scale (s1*64, s2*128).
        const int c2b = tN * 128 + wcol + rsel;
        int   h1c[4], h2c[4]; float s1c[4], s2c[4];
#pragma unroll
        for (int ni = 0; ni < 4; ++ni) {
            float4 cm = metaG[c2b + ni * 16];
            s1c[ni] = cm.x; h1c[ni] = __float_as_int(cm.y);
            s2c[ni] = cm.z; h2c[ni] = __float_as_int(cm.w);
        }

        // Scatter the 128x128 Gram tile into the LDS int histogram.
        // C/D layout (m89-verified): col = lane&15, row = (lane>>4)*4 + reg
        // Row meta also via VMEM -> zero lgkmcnt-ordered ops between ds_adds.
        // Both pairs of a diag-double accumulate into the same bins.
        const int rowbase = tM * 128 + wrow + (khi << 2);
#pragma unroll
        for (int mi = 0; mi < 4; ++mi) {
            float4 rm[4];
#pragma unroll
            for (int r = 0; r < 4; ++r) rm[r] = metaG[rowbase + mi * 16 + r];
#pragma unroll
            for (int r = 0; r < 4; ++r) {
                const float s1r = rm[r].x, s2r = rm[r].z;
                const int h1r = __float_as_int(rm[r].y);
                const int h2r = __float_as_int(rm[r].w);
#pragma unroll
                for (int ni = 0; ni < 4; ++ni) {
                    float g = acc[mi][ni][r];
                    atomicAdd(&bins[(h1r + h2c[ni]) & (DDIM - 1)],
                              (int)(s1r * s2c[ni] * g));
                    if (!diag)
                        atomicAdd(&bins[(h1c[ni] + h2r) & (DDIM - 1)],
                                  (int)(s1c[ni] * s2r * g));
                }
            }
        }
        // No barrier here: next pair's stage-0 __syncthreads orders all
        // waves' scatters before smA reuse (disjoint LDS regions anyway).
    }

    __syncthreads();   // all scatters into bins complete

    if (exclusive) {
        // Exclusive slot (slot_in_batch = bid>>3, unique per (slot,b)):
        // plain coalesced float4 stores through L2.
        float* pbase = part + ((size_t)((bid >> 3) * BATCH + b) * DDIM);
#pragma unroll 4
        for (int i = tid; i < DDIM / 4; i += 256) {
            int4 v = *(const int4*)&bins[i * 4];
            float4 f = make_float4((float)v.x * FXINV, (float)v.y * FXINV,
                                   (float)v.z * FXINV, (float)v.w * FXINV);
            *(float4*)&pbase[i * 4] = f;
        }
    } else {
        // Fallback: 64 shared slots, fp32 global atomics, rotated start.
        float* pbase = part + ((size_t)(((bid >> 3) & 63) * BATCH + b) * DDIM);
        const int rot = (bid & 31) << 8;
        for (int i = tid; i < DDIM; i += 256) {
            int j = (i + rot) & (DDIM - 1);
            int v = bins[j];
            if (v != 0) FATOMIC(&pbase[j], (float)v * FXINV);
        }
    }
}

// ---------------------------------------------------------------------------
// Kernel 3: y[b,d] = sum over nslots part slots; norm[b] += sum|y|.
// grid 256 x 256: one scalar float per thread, all CUs active.
// batch = blockIdx&7 keeps reads on the XCD whose L2 holds that batch's part.
// NOTE: overwrites y, whose first 32 KB doubled as metaG for the (already
// finished) gram kernel -- intentional workspace reuse.
// ---------------------------------------------------------------------------
__global__ __launch_bounds__(256) void reduce_kernel(
    const float* __restrict__ part, float* __restrict__ y,
    float* __restrict__ norm, int nslots)
{
    const int tid = threadIdx.x;
    const int b   = blockIdx.x & 7;
    const int d0  = (blockIdx.x >> 3) * 256 + tid;     // scalar float index
    float s = 0.0f;
#pragma unroll 8
    for (int p = 0; p < nslots; ++p)
        s += part[((size_t)p * BATCH + b) * DDIM + d0];
    y[(size_t)b * DDIM + d0] = s;
    float ab = fabsf(s);
    __shared__ float red[256];
    red[tid] = ab;
    __syncthreads();
    for (int st = 128; st > 0; st >>= 1) {
        if (tid < st) red[tid] += red[tid + st];
        __syncthreads();
    }
    if (tid == 0) FATOMIC(&norm[b], red[0]);   // sum|y| == sum feat_unnorm^2
}

// ---------------------------------------------------------------------------
// Kernel 4: fused signed-sqrt + L2-normalize + classifier GEMV.
// grid 128: block j owns d in [64j, 64j+64) for all batches (R10: doubles
// the CUs streaming the 6.6 MB W; inv-norm hoisted per batch).
// ---------------------------------------------------------------------------
__global__ __launch_bounds__(256) void logit_kernel(
    const float* __restrict__ y, const float* __restrict__ norm,
    const float* __restrict__ W, float* __restrict__ out)
{
    const int j = blockIdx.x;
    const int tid = threadIdx.x;
    __shared__ float fs[BATCH][64];                    // 2 KB
    __shared__ float inv[BATCH];
    if (tid < BATCH) inv[tid] = 1.0f / fmaxf(sqrtf(norm[tid]), 1e-12f);
    __syncthreads();
    for (int i = tid; i < BATCH * 64; i += 256) {
        int bb = i >> 6, dd = i & 63;
        float v = y[(size_t)bb * DDIM + j * 64 + dd];
        float f = copysignf(sqrtf(fabsf(v)), v) * inv[bb];
        fs[bb][dd] = f;
        out[BATCH * NCLS + (size_t)bb * DDIM + j * 64 + dd] = f;
    }
    __syncthreads();
    if (tid < NCLS) {
        float a[BATCH];
#pragma unroll
        for (int bb = 0; bb < BATCH; ++bb) a[bb] = 0.0f;
        for (int dd = 0; dd < 64; ++dd) {
            float w = W[(size_t)(j * 64 + dd) * NCLS + tid];
#pragma unroll
            for (int bb = 0; bb < BATCH; ++bb) a[bb] += fs[bb][dd] * w;
        }
#pragma unroll
        for (int bb = 0; bb < BATCH; ++bb)
            FATOMIC(&out[bb * NCLS + tid], a[bb]);
    }
}

// ---------------------------------------------------------------------------
extern "C" void kernel_launch(void* const* d_in, const int* in_sizes, int n_in,
                              void* d_out, int out_size, void* d_ws, size_t ws_size,
                              hipStream_t stream)
{
    const float* x  = (const float*)d_in[0];
    const float* s1 = (const float*)d_in[1];
    const float* s2 = (const float*)d_in[2];
    const float* W  = (const float*)d_in[3];
    const float* bc = (const float*)d_in[4];
    const int*   h1 = (const int*)d_in[5];
    const int*   h2 = (const int*)d_in[6];
    float* out = (float*)d_out;

    const size_t ybytes  = (size_t)BATCH * DDIM * sizeof(float);
    const size_t xhbytes = (size_t)BATCH * CH * KPAD * sizeof(_Float16);

    // Prefer exclusive mode: part = 128 slots/batch (32 MB), plain-store
    // flush. Fallback (ws too small): 64 shared slots + atomic flush.
    size_t partbytes = (size_t)NSLOTX * BATCH * DDIM * sizeof(float);
    int exclusive = (ws_size >= partbytes + ybytes + 128 + xhbytes);
    if (!exclusive)
        partbytes = (size_t)NSLOTF * BATCH * DDIM * sizeof(float);
    const int nslots = exclusive ? NSLOTX : NSLOTF;

    // ws layout: part | y (first 32KB doubles as metaG until reduce) | norm | xh
    char* ws = (char*)d_ws;
    float* part = (float*)ws;
    float* y    = (float*)(ws + partbytes);
    float4* metaG = (float4*)(ws + partbytes);         // overlay on y region
    float* norm = (float*)(ws + partbytes + ybytes);
    _Float16* xh = (_Float16*)(ws + partbytes + ybytes + 128);

    split_kernel<<<(BATCH * CH * KPAD / 8 + 255) / 256, 256, 0, stream>>>(
        x, xh, part, norm, s1, h1, s2, h2, metaG, bc, out, exclusive);

    gram_scatter_kernel<<<NGRID, 256, 0, stream>>>(
        xh, metaG, part, exclusive);

    reduce_kernel<<<256, 256, 0, stream>>>(part, y, norm, nslots);

    logit_kernel<<<128, 256, 0, stream>>>(y, norm, W, out);
}